// Round 9
// baseline (2819.446 us; speedup 1.0000x reference)
//
#include <hip/hip_runtime.h>

typedef __attribute__((ext_vector_type(8))) short bf16x8;
typedef __attribute__((ext_vector_type(4))) float f32x4;

#define T_ 1024
#define CH 32          // timesteps per chunk
#define NC 32          // chunks
#define TPC 256        // gemm tiles per chunk (128 b x 32 t / 16 rows)
#define NWORK 240      // worker blocks

// round-to-nearest-even f32 -> bf16 bits (scalar)
__device__ __forceinline__ unsigned short f2bf(float f) {
  unsigned int u = __float_as_uint(f);
  u += 0x7fffu + ((u >> 16) & 1u);
  return (unsigned short)(u >> 16);
}

// pack 2 f32 -> 2 bf16 (RNE), one instruction
__device__ __forceinline__ unsigned int cvtpk(float a, float b) {
  unsigned int r;
  asm("v_cvt_pk_bf16_f32 %0, %1, %2" : "=v"(r) : "v"(a), "v"(b));
  return r;
}

// tanh(x) = 1 - 2*rcp(1 + exp2(x * 2/ln2)); saturates to +-1, no NaN for finite x
__device__ __forceinline__ float tanh_fast(float x) {
  float e = __builtin_amdgcn_exp2f(x * 2.8853900817779268f);
  return __builtin_fmaf(-2.0f, __builtin_amdgcn_rcpf(1.0f + e), 1.0f);
}

#define BAR() asm volatile("s_waitcnt lgkmcnt(0)\n\ts_barrier" ::: "memory")
#define DRAIN() asm volatile("s_waitcnt vmcnt(0) lgkmcnt(0)" ::: "memory")

// ---- 4 weight matrices [256][256] f32 -> transposed bf16 [u][f], packed at d + w*65536 ----
__global__ __launch_bounds__(256) void k_cvt_w(const float* __restrict__ s0,
                                               const float* __restrict__ s1,
                                               const float* __restrict__ s2,
                                               const float* __restrict__ s3,
                                               unsigned short* __restrict__ d) {
  int w = blockIdx.x >> 8, f = blockIdx.x & 255, u = threadIdx.x;
  const float* s = w == 0 ? s0 : w == 1 ? s1 : w == 2 ? s2 : s3;
  d[w * 65536 + u * 256 + f] = f2bf(s[f * 256 + u]);
}

// Permuted activation layouts (scan-coalesced):
//   xp   f32 : element (b,t,n) at ((t*8+g)*4096) + (n>>4)*256 + (b&15)*16 + (n&15),  g=b>>4
//   hseq bf16: element (b,t,k) at ((t*8+g)*4096) + (k>>4)*256 + (b&15)*16 + (k&15)
// A scan wave (fixed g,t, n-tile) then loads/stores one fully contiguous 1KB/512B block.

// ---- persistent 3-role pipeline: enc scan (blk 0-7) | dec scan (blk 8-15) | gemm workers ----
// All 256 blocks co-resident (512 thr, 16KB LDS, <=256 VGPR -> 1 block/CU exactly).
// Workers phase A: xpe tiles (x @ enc_Wx + enc_b -> xp perm), chunk-ordered, publish xpe_ctr.
// Enc: slim scan gated on xpe_ctr; streams h_t to hseq perm (coalesced); publishes enc_ctr/chunk.
// Workers phase B: proj tiles (hseq @ dec_Wx + dec_b -> xp perm, ALIASING xpe chunk c --
//   safe: gated on enc_ctr[c], enc has fully consumed+drained xpe[c]); publish xpq_ctr.
// Dec: slim scan gated on xpq_ctr; final tanh f32 -> out.
// Sync recipe per r5 (proven correct cross-XCD): producer DRAIN+barrier+tid0 release-add
// agent-scope; consumer tid0 acquire-poll (+s_sleep) + barrier + agent acquire fence.
__global__ __launch_bounds__(512, 2) void k_pipe(const float* __restrict__ x,
                                                 const unsigned short* __restrict__ wT,
                                                 const float* __restrict__ enc_b,
                                                 const float* __restrict__ dec_b,
                                                 float* __restrict__ xp,
                                                 unsigned short* __restrict__ hseq,
                                                 float* __restrict__ out,
                                                 unsigned int* __restrict__ ctr) {
  __shared__ __align__(16) char hb[16384];
  const int tid = threadIdx.x, wave = tid >> 6, lane = tid & 63;
  const int lo = lane & 15, hi = lane >> 4;
  unsigned int* xpe_ctr = ctr;        // [32], counts phase-A tiles per chunk (==TPC when ready)
  unsigned int* enc_ctr = ctr + 32;   // [32], counts enc groups done per chunk (==8 when ready)
  unsigned int* xpq_ctr = ctr + 64;   // [32], counts phase-B tiles per chunk
  const int bidx = blockIdx.x;

  auto block_wait = [&](unsigned int* p, unsigned int v) {
    if (tid == 0) {
      while (__hip_atomic_load(p, __ATOMIC_ACQUIRE, __HIP_MEMORY_SCOPE_AGENT) < v)
        __builtin_amdgcn_s_sleep(2);
    }
    __syncthreads();
    __builtin_amdgcn_fence(__ATOMIC_ACQUIRE, "agent");
  };
  auto publish = [&](unsigned int* p) {
    DRAIN();
    __syncthreads();
    if (tid == 0)
      __hip_atomic_fetch_add(p, 1u, __ATOMIC_RELEASE, __HIP_MEMORY_SCOPE_AGENT);
  };

  if (bidx >= 16) {
    // ================= GEMM workers =================
    const int wb = bidx - 16;
    const int n0 = wave * 32;
    bf16x8 aW[2][8];
    f32x4 bias[2];
    // ---- phase A: xpe = x @ enc_Wx + enc_b ----
#pragma unroll
    for (int nt = 0; nt < 2; ++nt) {
#pragma unroll
      for (int kt = 0; kt < 8; ++kt)
        aW[nt][kt] = *(const bf16x8*)(wT + (size_t)(n0 + nt * 16 + lo) * 256 + kt * 32 + hi * 8);
      bias[nt] = *(const f32x4*)(enc_b + n0 + nt * 16 + hi * 4);
    }
    for (int i = wb; i < 8192; i += NWORK) {
      const int c = i >> 8, r = i & 255, b = r >> 1, t0 = c * CH + (r & 1) * 16;
      const float* Ap = x + ((size_t)b * T_ + t0 + lo) * 256 + hi * 8;
      bf16x8 bb[8];
#pragma unroll
      for (int kt = 0; kt < 8; ++kt) {
        float4 u = *(const float4*)(Ap + kt * 32);
        float4 v = *(const float4*)(Ap + kt * 32 + 4);
        union { bf16x8 v8; unsigned int w[4]; } rr;
        rr.w[0] = cvtpk(u.x, u.y); rr.w[1] = cvtpk(u.z, u.w);
        rr.w[2] = cvtpk(v.x, v.y); rr.w[3] = cvtpk(v.z, v.w);
        bb[kt] = rr.v8;
      }
      const size_t obase = ((size_t)(t0 + lo) * 8 + (b >> 4)) * 4096 + (b & 15) * 16 + hi * 4;
#pragma unroll
      for (int nt = 0; nt < 2; ++nt) {
        f32x4 acc = bias[nt];
#pragma unroll
        for (int kt = 0; kt < 8; ++kt)
          acc = __builtin_amdgcn_mfma_f32_16x16x32_bf16(aW[nt][kt], bb[kt], acc, 0, 0, 0);
        *(f32x4*)(xp + obase + (wave * 2 + nt) * 256) = acc;
      }
      publish(&xpe_ctr[c]);
    }
    // ---- phase B: xpq = hseq @ dec_Wx + dec_b (into the same xp buffer) ----
#pragma unroll
    for (int nt = 0; nt < 2; ++nt) {
#pragma unroll
      for (int kt = 0; kt < 8; ++kt)
        aW[nt][kt] = *(const bf16x8*)(wT + 131072 + (size_t)(n0 + nt * 16 + lo) * 256 + kt * 32 + hi * 8);
      bias[nt] = *(const f32x4*)(dec_b + n0 + nt * 16 + hi * 4);
    }
    int lastc = -1;
    for (int i = wb; i < 8192; i += NWORK) {
      const int c = i >> 8, r = i & 255, b = r >> 1, t0 = c * CH + (r & 1) * 16;
      if (c != lastc) { block_wait(&enc_ctr[c], 8u); lastc = c; }
      const unsigned short* hrow =
          hseq + ((size_t)(t0 + lo) * 8 + (b >> 4)) * 4096 + (b & 15) * 16 + (hi & 1) * 8;
      bf16x8 bb[8];
#pragma unroll
      for (int kt = 0; kt < 8; ++kt)
        bb[kt] = *(const bf16x8*)(hrow + (2 * kt + (hi >> 1)) * 256);
      const size_t obase = ((size_t)(t0 + lo) * 8 + (b >> 4)) * 4096 + (b & 15) * 16 + hi * 4;
#pragma unroll
      for (int nt = 0; nt < 2; ++nt) {
        f32x4 acc = bias[nt];
#pragma unroll
        for (int kt = 0; kt < 8; ++kt)
          acc = __builtin_amdgcn_mfma_f32_16x16x32_bf16(aW[nt][kt], bb[kt], acc, 0, 0, 0);
        *(f32x4*)(xp + obase + (wave * 2 + nt) * 256) = acc;
      }
      publish(&xpq_ctr[c]);
    }
    return;
  }

  // ================= scans (enc: bidx 0-7, dec: bidx 8-15) =================
  const bool enc = bidx < 8;
  const int g = enc ? bidx : bidx - 8;
  const int n0 = wave * 32;
  const unsigned short* WhT = wT + (enc ? 65536 : 196608);

  bf16x8 ah[2][8];
#pragma unroll
  for (int nt = 0; nt < 2; ++nt)
#pragma unroll
    for (int kt = 0; kt < 8; ++kt)
      ah[nt][kt] = *(const bf16x8*)(WhT + (size_t)(n0 + nt * 16 + lo) * 256 + kt * 32 + hi * 8);

  for (int i = tid; i < 4096; i += 512) ((unsigned int*)hb)[i] = 0;
  __syncthreads();

  const int swz = (lo & 7) << 4;
  int raddr[8];
#pragma unroll
  for (int kt = 0; kt < 8; ++kt) raddr[kt] = (lo * 512 + kt * 64 + hi * 16) ^ swz;
  int waddr[2];
#pragma unroll
  for (int nt = 0; nt < 2; ++nt)
    waddr[nt] = (lo * 512 + (n0 + nt * 16 + hi * 4) * 2) ^ swz;

  // permuted per-thread offsets (contiguous per wave)
  const int poff0 = (wave * 2) * 256 + lo * 16 + hi * 4;
  const int poff1 = (wave * 2 + 1) * 256 + lo * 16 + hi * 4;

  unsigned int* gate = enc ? xpe_ctr : xpq_ctr;
  block_wait(&gate[1], TPC);  // covers chunks 0-1 incl. prefetch spill

  f32x4 xva[2], xvb[2];
  {
    const float* p0 = xp + (size_t)(0 * 8 + g) * 4096;
    const float* p1 = xp + (size_t)(1 * 8 + g) * 4096;
    xva[0] = *(const f32x4*)(p0 + poff0); xva[1] = *(const f32x4*)(p0 + poff1);
    xvb[0] = *(const f32x4*)(p1 + poff0); xvb[1] = *(const f32x4*)(p1 + poff1);
  }

  auto step = [&](int t, f32x4 (&xv)[2], int ro, int wo) {
    bf16x8 b[8];
#pragma unroll
    for (int kt = 0; kt < 8; ++kt) b[kt] = *(const bf16x8*)(hb + ro + raddr[kt]);
    f32x4 c0 = xv[0], c1 = xv[1];
#pragma unroll
    for (int kt = 0; kt < 8; ++kt) {
      c0 = __builtin_amdgcn_mfma_f32_16x16x32_bf16(ah[0][kt], b[kt], c0, 0, 0, 0);
      c1 = __builtin_amdgcn_mfma_f32_16x16x32_bf16(ah[1][kt], b[kt], c1, 0, 0, 0);
    }
    {  // refill this parity for t+2 (in flight across lgkm-only barriers)
      const int tn = (t + 2 <= T_ - 1) ? t + 2 : T_ - 1;
      const float* pb = xp + ((size_t)tn * 8 + g) * 4096;
      xv[0] = *(const f32x4*)(pb + poff0);
      xv[1] = *(const f32x4*)(pb + poff1);
    }
    float th[8];
#pragma unroll
    for (int q = 0; q < 8; ++q) th[q] = tanh_fast(q < 4 ? c0[q] : c1[q - 4]);
    uint2 w0 = {cvtpk(th[0], th[1]), cvtpk(th[2], th[3])};
    uint2 w1 = {cvtpk(th[4], th[5]), cvtpk(th[6], th[7])};
    if (enc) {  // coalesced hseq store (512B contiguous per wave)
      unsigned short* hp = hseq + ((size_t)t * 8 + g) * 4096;
      *(uint2*)(hp + poff0) = w0;
      *(uint2*)(hp + poff1) = w1;
    } else if (t == T_ - 1) {  // final hidden state, f32 [128][256]
      float* op = out + (size_t)(g * 16 + lo) * 256 + n0 + hi * 4;
      f32x4 o0 = {th[0], th[1], th[2], th[3]};
      f32x4 o1 = {th[4], th[5], th[6], th[7]};
      *(f32x4*)(op) = o0;
      *(f32x4*)(op + 16) = o1;
    }
    *(uint2*)(hb + wo + waddr[0]) = w0;
    *(uint2*)(hb + wo + waddr[1]) = w1;
    BAR();
  };

  for (int c = 0; c < NC; ++c) {
    if (c) {  // chunk c's steps prefetch into chunk c+1
      const int cw = (c + 1 < NC) ? c + 1 : NC - 1;
      block_wait(&gate[cw], TPC);
    }
    for (int tt = 0; tt < CH; tt += 2) {
      const int t = c * CH + tt;
      step(t, xva, 8192, 0);
      step(t + 1, xvb, 0, 8192);
    }
    if (enc) publish(&enc_ctr[c]);
  }
}

extern "C" void kernel_launch(void* const* d_in, const int* in_sizes, int n_in,
                              void* d_out, int out_size, void* d_ws, size_t ws_size,
                              hipStream_t stream) {
  const float* x      = (const float*)d_in[0];
  const float* enc_Wx = (const float*)d_in[1];
  const float* enc_Wh = (const float*)d_in[2];
  const float* enc_b  = (const float*)d_in[3];
  const float* dec_Wx = (const float*)d_in[4];
  const float* dec_Wh = (const float*)d_in[5];
  const float* dec_b  = (const float*)d_in[6];

  char* ws = (char*)d_ws;
  float*          xp   = (float*)ws;                                  // 128MB perm xp (enc then dec, chunk-aliased)
  unsigned short* hseq = (unsigned short*)(ws + ((size_t)128 << 20)); // 64MB perm bf16 h_seq
  unsigned short* wT   = (unsigned short*)(ws + ((size_t)192 << 20)); // 4 x 128KB bf16 W^T
  unsigned int*   ctr  = (unsigned int*)(ws + ((size_t)193 << 20));   // 96 x u32 chunk counters

  // counters must be zero at every call (replay-safe)
  (void)hipMemsetAsync(ctr, 0, 512, stream);
  // wT layout: [0]=enc_Wx^T  [1]=enc_Wh^T  [2]=dec_Wx^T  [3]=dec_Wh^T
  k_cvt_w<<<1024, 256, 0, stream>>>(enc_Wx, enc_Wh, dec_Wx, dec_Wh, wT);
  // persistent pipeline: enc scan | dec scan | gemm workers (exactly 1 block/CU)
  k_pipe<<<256, 512, 0, stream>>>(x, wT, enc_b, dec_b, xp, hseq, (float*)d_out, ctr);
}

// Round 10
// 1395.493 us; speedup vs baseline: 2.0204x; 2.0204x over previous
//
#include <hip/hip_runtime.h>

typedef __attribute__((ext_vector_type(8))) short bf16x8;
typedef __attribute__((ext_vector_type(4))) float f32x4;

#define T_ 1024

// round-to-nearest-even f32 -> bf16 bits (scalar)
__device__ __forceinline__ unsigned short f2bf(float f) {
  unsigned int u = __float_as_uint(f);
  u += 0x7fffu + ((u >> 16) & 1u);
  return (unsigned short)(u >> 16);
}

// pack 2 f32 -> 2 bf16 (RNE), one instruction
__device__ __forceinline__ unsigned int cvtpk(float a, float b) {
  unsigned int r;
  asm("v_cvt_pk_bf16_f32 %0, %1, %2" : "=v"(r) : "v"(a), "v"(b));
  return r;
}

// tanh(x) = 1 - 2*rcp(1 + exp2(x * 2/ln2)); saturates to +-1, no NaN for finite x
__device__ __forceinline__ float tanh_fast(float x) {
  float e = __builtin_amdgcn_exp2f(x * 2.8853900817779268f);
  return __builtin_fmaf(-2.0f, __builtin_amdgcn_rcpf(1.0f + e), 1.0f);
}

#define BAR() asm volatile("s_waitcnt lgkmcnt(0)\n\ts_barrier" ::: "memory")

// Permuted activation layouts (scan-coalesced); g = b>>4, block index bid = t*8+g:
//   xp   f32 : (b,t,n) at bid*4096 + (n>>4)*256 + (b&15)*16 + (n&15)
//   hseq bf16: (b,t,k) at bid*4096 + (k>>4)*256 + (b&15)*16 + (k&15)
// A scan wave (fixed g,t, 32-n slice) then touches one contiguous 1KB/512B block,
// and a (g,t)-tile GEMM block stores one contiguous 4KB block.

// ---- 4 weight matrices [256][256] f32 -> transposed bf16 [u][f], packed at d + w*65536 ----
__global__ __launch_bounds__(256) void k_cvt_w(const float* __restrict__ s0,
                                               const float* __restrict__ s1,
                                               const float* __restrict__ s2,
                                               const float* __restrict__ s3,
                                               unsigned short* __restrict__ d) {
  int w = blockIdx.x >> 8, f = blockIdx.x & 255, u = threadIdx.x;
  const float* s = w == 0 ? s0 : w == 1 ? s1 : w == 2 ? s2 : s3;
  d[w * 65536 + u * 256 + f] = f2bf(s[f * 256 + u]);
}

// ---- xp[bid] = x[g*16..+16][t] @ enc_Wx + enc_b  (swapped operands, permuted C) ----
// 8192 blocks (bid = t*8+g) x 256 thr (4 waves); wave owns n in [64w, 64w+64).
__global__ __launch_bounds__(256) void k_gemm_x(const float* __restrict__ x,
                                                const unsigned short* __restrict__ WT,
                                                const float* __restrict__ bias,
                                                float* __restrict__ xp) {
  const int wave = threadIdx.x >> 6, lane = threadIdx.x & 63;
  const int lo = lane & 15, hi = lane >> 4;
  const int n0 = wave * 64;
  const int bid = blockIdx.x, g = bid & 7, t = bid >> 3;

  bf16x8 a[4][8];
#pragma unroll
  for (int nt = 0; nt < 4; ++nt)
#pragma unroll
    for (int kt = 0; kt < 8; ++kt)
      a[nt][kt] = *(const bf16x8*)(WT + (size_t)(n0 + nt * 16 + lo) * 256 + kt * 32 + hi * 8);

  // B-frags: row b = g*16+lo at timestep t (rows 1MB apart -- scatter, TLP-absorbed)
  const float* Ap = x + ((size_t)(g * 16 + lo) * T_ + t) * 256 + hi * 8;
  bf16x8 b[8];
#pragma unroll
  for (int kt = 0; kt < 8; ++kt) {
    float4 u = *(const float4*)(Ap + kt * 32);
    float4 v = *(const float4*)(Ap + kt * 32 + 4);
    union { bf16x8 v8; unsigned int w[4]; } r;
    r.w[0] = cvtpk(u.x, u.y); r.w[1] = cvtpk(u.z, u.w);
    r.w[2] = cvtpk(v.x, v.y); r.w[3] = cvtpk(v.z, v.w);
    b[kt] = r.v8;
  }

  float* Cb = xp + (size_t)bid * 4096;  // one contiguous 4KB block
#pragma unroll
  for (int nt = 0; nt < 4; ++nt) {
    f32x4 acc = *(const f32x4*)(bias + n0 + nt * 16 + hi * 4);
#pragma unroll
    for (int kt = 0; kt < 8; ++kt)
      acc = __builtin_amdgcn_mfma_f32_16x16x32_bf16(a[nt][kt], b[kt], acc, 0, 0, 0);
    *(f32x4*)(Cb + (wave * 4 + nt) * 256 + lo * 16 + hi * 4) = acc;
  }
}

// ---- xpd[bid] = hseq[bid] @ dec_Wx + dec_b  (A-data read AND C-store both contiguous) ----
__global__ __launch_bounds__(256) void k_gemm_h(const unsigned short* __restrict__ hseq,
                                                const unsigned short* __restrict__ WT,
                                                const float* __restrict__ bias,
                                                float* __restrict__ xpd) {
  const int wave = threadIdx.x >> 6, lane = threadIdx.x & 63;
  const int lo = lane & 15, hi = lane >> 4;
  const int n0 = wave * 64;
  const int bid = blockIdx.x;

  bf16x8 a[4][8];
#pragma unroll
  for (int nt = 0; nt < 4; ++nt)
#pragma unroll
    for (int kt = 0; kt < 8; ++kt)
      a[nt][kt] = *(const bf16x8*)(WT + (size_t)(n0 + nt * 16 + lo) * 256 + kt * 32 + hi * 8);

  // B-frags from permuted hseq: row lo, k = kt*32 + hi*8 + j -> contiguous 16B reads
  const unsigned short* Hp = hseq + (size_t)bid * 4096 + lo * 16 + (hi & 1) * 8;
  bf16x8 b[8];
#pragma unroll
  for (int kt = 0; kt < 8; ++kt)
    b[kt] = *(const bf16x8*)(Hp + (2 * kt + (hi >> 1)) * 256);

  float* Cb = xpd + (size_t)bid * 4096;
#pragma unroll
  for (int nt = 0; nt < 4; ++nt) {
    f32x4 acc = *(const f32x4*)(bias + n0 + nt * 16 + hi * 4);
#pragma unroll
    for (int kt = 0; kt < 8; ++kt)
      acc = __builtin_amdgcn_mfma_f32_16x16x32_bf16(a[nt][kt], b[kt], acc, 0, 0, 0);
    *(f32x4*)(Cb + (wave * 4 + nt) * 256 + lo * 16 + hi * 4) = acc;
  }
}

// ---- recurrent scan: h_t = tanh(xp_t + h_{t-1} @ Wh), 8-wave lockstep, permuted I/O ----
// 8 WGs x 512 thr (8 waves, 2/SIMD -- the empirically best structure: r3/r7 1450-1580
// cyc/step); WG owns group g (16 batch rows); wave owns n in [32w, 32w+32).
// Weights VGPR-resident. h tile [16 b][256 k] bf16 in LDS, double-buffered, XOR-swizzled.
// One raw lgkm-only barrier per step; xp prefetch distance-2 and hseq stores in flight.
// All global accesses contiguous per wave (1KB loads / 512B stores) via permuted layout.
template <bool HSEQ>
__global__ __launch_bounds__(512, 2) void k_scan(const float* __restrict__ xp,
                                                 const unsigned short* __restrict__ WhT,
                                                 unsigned short* __restrict__ hseq,
                                                 float* __restrict__ out) {
  __shared__ __align__(16) char hb[16384];  // [2][16 b][256 k] bf16
  const int tid = threadIdx.x, wave = tid >> 6, lane = tid & 63;
  const int lo = lane & 15, hi = lane >> 4;
  const int g = blockIdx.x;
  const int n0 = wave * 32;

  bf16x8 ah[2][8];
#pragma unroll
  for (int nt = 0; nt < 2; ++nt)
#pragma unroll
    for (int kt = 0; kt < 8; ++kt)
      ah[nt][kt] = *(const bf16x8*)(WhT + (size_t)(n0 + nt * 16 + lo) * 256 + kt * 32 + hi * 8);

  for (int i = tid; i < 4096; i += 512) ((unsigned int*)hb)[i] = 0;
  __syncthreads();

  const int swz = (lo & 7) << 4;
  int raddr[8];
#pragma unroll
  for (int kt = 0; kt < 8; ++kt) raddr[kt] = (lo * 512 + kt * 64 + hi * 16) ^ swz;
  int waddr[2];
#pragma unroll
  for (int nt = 0; nt < 2; ++nt)
    waddr[nt] = (lo * 512 + (n0 + nt * 16 + hi * 4) * 2) ^ swz;

  // permuted per-thread offsets: wave's slice is contiguous (poff in [wave*512, wave*512+512))
  const int poff0 = (wave * 2) * 256 + lo * 16 + hi * 4;
  const int poff1 = (wave * 2 + 1) * 256 + lo * 16 + hi * 4;
  const float* xpg = xp + (size_t)g * 4096;          // + t*32768 per step
  unsigned short* hsg = HSEQ ? (hseq + (size_t)g * 4096) : nullptr;

  f32x4 xva[2], xvb[2];
  xva[0] = *(const f32x4*)(xpg + poff0);
  xva[1] = *(const f32x4*)(xpg + poff1);
  xvb[0] = *(const f32x4*)(xpg + 32768 + poff0);
  xvb[1] = *(const f32x4*)(xpg + 32768 + poff1);

  auto step = [&](int t, f32x4 (&xv)[2], int ro, int wo) {
    bf16x8 b[8];
#pragma unroll
    for (int kt = 0; kt < 8; ++kt) b[kt] = *(const bf16x8*)(hb + ro + raddr[kt]);
    f32x4 c0 = xv[0], c1 = xv[1];
#pragma unroll
    for (int kt = 0; kt < 8; ++kt) {
      c0 = __builtin_amdgcn_mfma_f32_16x16x32_bf16(ah[0][kt], b[kt], c0, 0, 0, 0);
      c1 = __builtin_amdgcn_mfma_f32_16x16x32_bf16(ah[1][kt], b[kt], c1, 0, 0, 0);
    }
    {  // refill this parity for t+2 (in flight across the lgkm-only barrier)
      const int tn = (t + 2 <= T_ - 1) ? t + 2 : T_ - 1;
      const float* pb = xpg + (size_t)tn * 32768;
      xv[0] = *(const f32x4*)(pb + poff0);
      xv[1] = *(const f32x4*)(pb + poff1);
    }
    float th[8];
#pragma unroll
    for (int q = 0; q < 8; ++q) th[q] = tanh_fast(q < 4 ? c0[q] : c1[q - 4]);
    uint2 w0 = {cvtpk(th[0], th[1]), cvtpk(th[2], th[3])};
    uint2 w1 = {cvtpk(th[4], th[5]), cvtpk(th[6], th[7])};
    *(uint2*)(hb + wo + waddr[0]) = w0;
    *(uint2*)(hb + wo + waddr[1]) = w1;
    if (HSEQ) {  // contiguous 512B/wave store, never drained
      unsigned short* hp = hsg + (size_t)t * 32768;
      *(uint2*)(hp + poff0) = w0;
      *(uint2*)(hp + poff1) = w1;
    } else if (t == T_ - 1) {  // final hidden state, f32 [128][256] (once)
      float* op = out + (size_t)(g * 16 + lo) * 256 + n0 + hi * 4;
      f32x4 o0 = {th[0], th[1], th[2], th[3]};
      f32x4 o1 = {th[4], th[5], th[6], th[7]};
      *(f32x4*)(op) = o0;
      *(f32x4*)(op + 16) = o1;
    }
    BAR();
  };

  for (int t = 0; t < T_; t += 2) {
    step(t, xva, 8192, 0);      // even: read buf1, write buf0
    step(t + 1, xvb, 0, 8192);  // odd:  read buf0, write buf1
  }
}

extern "C" void kernel_launch(void* const* d_in, const int* in_sizes, int n_in,
                              void* d_out, int out_size, void* d_ws, size_t ws_size,
                              hipStream_t stream) {
  const float* x      = (const float*)d_in[0];
  const float* enc_Wx = (const float*)d_in[1];
  const float* enc_Wh = (const float*)d_in[2];
  const float* enc_b  = (const float*)d_in[3];
  const float* dec_Wx = (const float*)d_in[4];
  const float* dec_Wh = (const float*)d_in[5];
  const float* dec_b  = (const float*)d_in[6];

  char* ws = (char*)d_ws;
  float*          xp   = (float*)ws;                                  // 128MB perm xp_enc (reused as xp_dec)
  unsigned short* hseq = (unsigned short*)(ws + ((size_t)128 << 20)); // 64MB perm bf16 h_seq
  unsigned short* wT   = (unsigned short*)(ws + ((size_t)192 << 20)); // 4 x 128KB bf16 W^T

  // wT layout: [0]=enc_Wx^T  [1]=enc_Wh^T  [2]=dec_Wx^T  [3]=dec_Wh^T
  k_cvt_w<<<1024, 256, 0, stream>>>(enc_Wx, enc_Wh, dec_Wx, dec_Wh, wT);
  // xp_enc = x @ enc_Wx + enc_b  (permuted C)
  k_gemm_x<<<8192, 256, 0, stream>>>(x, wT, enc_b, xp);
  // encoder scan -> h_seq (permuted bf16)
  k_scan<true><<<8, 512, 0, stream>>>(xp, wT + 65536, hseq, nullptr);
  // xp_dec = h_seq @ dec_Wx + dec_b  (permuted A and C; overwrites xp)
  k_gemm_h<<<8192, 256, 0, stream>>>(hseq, wT + 131072, dec_b, xp);
  // decoder scan -> final hidden state (f32) to d_out
  k_scan<false><<<8, 512, 0, stream>>>(xp, wT + 196608, nullptr, (float*)d_out);
}

// Round 11
// 1247.256 us; speedup vs baseline: 2.2605x; 1.1189x over previous
//
#include <hip/hip_runtime.h>

typedef __attribute__((ext_vector_type(8))) short bf16x8;
typedef __attribute__((ext_vector_type(4))) float f32x4;

#define T_ 1024

// round-to-nearest-even f32 -> bf16 bits (scalar)
__device__ __forceinline__ unsigned short f2bf(float f) {
  unsigned int u = __float_as_uint(f);
  u += 0x7fffu + ((u >> 16) & 1u);
  return (unsigned short)(u >> 16);
}

// pack 2 f32 -> 2 bf16 (RNE), one instruction
__device__ __forceinline__ unsigned int cvtpk(float a, float b) {
  unsigned int r;
  asm("v_cvt_pk_bf16_f32 %0, %1, %2" : "=v"(r) : "v"(a), "v"(b));
  return r;
}

// tanh(x) = 1 - 2*rcp(1 + exp2(x * 2/ln2)); saturates to +-1, no NaN for finite x
__device__ __forceinline__ float tanh_fast(float x) {
  float e = __builtin_amdgcn_exp2f(x * 2.8853900817779268f);
  return __builtin_fmaf(-2.0f, __builtin_amdgcn_rcpf(1.0f + e), 1.0f);
}

#define BAR() asm volatile("s_waitcnt lgkmcnt(0)\n\ts_barrier" ::: "memory")

// Permuted activation layouts (scan-coalesced); g = b>>4, block index bid = t*8+g:
//   xp   f32 : (b,t,n) at bid*4096 + (n>>4)*256 + (b&15)*16 + (n&15)
//   hseq bf16: (b,t,k) at bid*4096 + (k>>4)*256 + (b&15)*16 + (k&15)
// A scan wave (fixed g,t, 32-n slice) touches one contiguous 1KB/512B block;
// a (g,t)-tile GEMM store is one contiguous 4KB block.

// ---- 4 weight matrices [256][256] f32 -> transposed bf16 [u][f], packed at d + w*65536 ----
__global__ __launch_bounds__(256) void k_cvt_w(const float* __restrict__ s0,
                                               const float* __restrict__ s1,
                                               const float* __restrict__ s2,
                                               const float* __restrict__ s3,
                                               unsigned short* __restrict__ d) {
  int w = blockIdx.x >> 8, f = blockIdx.x & 255, u = threadIdx.x;
  const float* s = w == 0 ? s0 : w == 1 ? s1 : w == 2 ? s2 : s3;
  d[w * 65536 + u * 256 + f] = f2bf(s[f * 256 + u]);
}

// ---- xp[t*8+g] = x[g*16..+16][t] @ enc_Wx + enc_b, 16 timesteps per block ----
// 512 blocks (g = bid&7, t-chunk = bid>>3) x 256 thr (4 waves); wave owns 64 n.
// Weights loaded ONCE per block (16x amortization vs per-tile blocks).
__global__ __launch_bounds__(256) void k_gemm_x(const float* __restrict__ x,
                                                const unsigned short* __restrict__ WT,
                                                const float* __restrict__ bias,
                                                float* __restrict__ xp) {
  const int wave = threadIdx.x >> 6, lane = threadIdx.x & 63;
  const int lo = lane & 15, hi = lane >> 4;
  const int n0 = wave * 64;
  const int g = blockIdx.x & 7, t0 = (blockIdx.x >> 3) * 16;

  bf16x8 a[4][8];
  f32x4 bv[4];
#pragma unroll
  for (int nt = 0; nt < 4; ++nt) {
#pragma unroll
    for (int kt = 0; kt < 8; ++kt)
      a[nt][kt] = *(const bf16x8*)(WT + (size_t)(n0 + nt * 16 + lo) * 256 + kt * 32 + hi * 8);
    bv[nt] = *(const f32x4*)(bias + n0 + nt * 16 + hi * 4);
  }

  const float* xrow = x + ((size_t)(g * 16 + lo) * T_ + t0) * 256 + hi * 8;
  for (int tt = 0; tt < 16; ++tt) {
    const float* Ap = xrow + (size_t)tt * 256;
    bf16x8 b[8];
#pragma unroll
    for (int kt = 0; kt < 8; ++kt) {
      float4 u = *(const float4*)(Ap + kt * 32);
      float4 v = *(const float4*)(Ap + kt * 32 + 4);
      union { bf16x8 v8; unsigned int w[4]; } r;
      r.w[0] = cvtpk(u.x, u.y); r.w[1] = cvtpk(u.z, u.w);
      r.w[2] = cvtpk(v.x, v.y); r.w[3] = cvtpk(v.z, v.w);
      b[kt] = r.v8;
    }
    float* Cb = xp + (size_t)((t0 + tt) * 8 + g) * 4096;
#pragma unroll
    for (int nt = 0; nt < 4; ++nt) {
      f32x4 acc = bv[nt];
#pragma unroll
      for (int kt = 0; kt < 8; ++kt)
        acc = __builtin_amdgcn_mfma_f32_16x16x32_bf16(a[nt][kt], b[kt], acc, 0, 0, 0);
      *(f32x4*)(Cb + (wave * 4 + nt) * 256 + lo * 16 + hi * 4) = acc;
    }
  }
}

// ---- xpd[bid] = hseq[bid] @ dec_Wx + dec_b, 16 tiles per block (perm A and C) ----
__global__ __launch_bounds__(256) void k_gemm_h(const unsigned short* __restrict__ hseq,
                                                const unsigned short* __restrict__ WT,
                                                const float* __restrict__ bias,
                                                float* __restrict__ xpd) {
  const int wave = threadIdx.x >> 6, lane = threadIdx.x & 63;
  const int lo = lane & 15, hi = lane >> 4;
  const int n0 = wave * 64;
  const int g = blockIdx.x & 7, t0 = (blockIdx.x >> 3) * 16;

  bf16x8 a[4][8];
  f32x4 bv[4];
#pragma unroll
  for (int nt = 0; nt < 4; ++nt) {
#pragma unroll
    for (int kt = 0; kt < 8; ++kt)
      a[nt][kt] = *(const bf16x8*)(WT + (size_t)(n0 + nt * 16 + lo) * 256 + kt * 32 + hi * 8);
    bv[nt] = *(const f32x4*)(bias + n0 + nt * 16 + hi * 4);
  }

  for (int tt = 0; tt < 16; ++tt) {
    const size_t bid = (size_t)(t0 + tt) * 8 + g;
    const unsigned short* Hp = hseq + bid * 4096 + lo * 16 + (hi & 1) * 8;
    bf16x8 b[8];
#pragma unroll
    for (int kt = 0; kt < 8; ++kt)
      b[kt] = *(const bf16x8*)(Hp + (2 * kt + (hi >> 1)) * 256);
    float* Cb = xpd + bid * 4096;
#pragma unroll
    for (int nt = 0; nt < 4; ++nt) {
      f32x4 acc = bv[nt];
#pragma unroll
      for (int kt = 0; kt < 8; ++kt)
        acc = __builtin_amdgcn_mfma_f32_16x16x32_bf16(a[nt][kt], b[kt], acc, 0, 0, 0);
      *(f32x4*)(Cb + (wave * 4 + nt) * 256 + lo * 16 + hi * 4) = acc;
    }
  }
}

// ---- recurrent scan: h_t = tanh(xp_t + h_{t-1} @ Wh), 8-wave lockstep, permuted I/O ----
// (unchanged from round 10: 571 us, 1335 cyc/step measured)
template <bool HSEQ>
__global__ __launch_bounds__(512, 2) void k_scan(const float* __restrict__ xp,
                                                 const unsigned short* __restrict__ WhT,
                                                 unsigned short* __restrict__ hseq,
                                                 float* __restrict__ out) {
  __shared__ __align__(16) char hb[16384];  // [2][16 b][256 k] bf16
  const int tid = threadIdx.x, wave = tid >> 6, lane = tid & 63;
  const int lo = lane & 15, hi = lane >> 4;
  const int g = blockIdx.x;
  const int n0 = wave * 32;

  bf16x8 ah[2][8];
#pragma unroll
  for (int nt = 0; nt < 2; ++nt)
#pragma unroll
    for (int kt = 0; kt < 8; ++kt)
      ah[nt][kt] = *(const bf16x8*)(WhT + (size_t)(n0 + nt * 16 + lo) * 256 + kt * 32 + hi * 8);

  for (int i = tid; i < 4096; i += 512) ((unsigned int*)hb)[i] = 0;
  __syncthreads();

  const int swz = (lo & 7) << 4;
  int raddr[8];
#pragma unroll
  for (int kt = 0; kt < 8; ++kt) raddr[kt] = (lo * 512 + kt * 64 + hi * 16) ^ swz;
  int waddr[2];
#pragma unroll
  for (int nt = 0; nt < 2; ++nt)
    waddr[nt] = (lo * 512 + (n0 + nt * 16 + hi * 4) * 2) ^ swz;

  const int poff0 = (wave * 2) * 256 + lo * 16 + hi * 4;
  const int poff1 = (wave * 2 + 1) * 256 + lo * 16 + hi * 4;
  const float* xpg = xp + (size_t)g * 4096;
  unsigned short* hsg = HSEQ ? (hseq + (size_t)g * 4096) : nullptr;

  f32x4 xva[2], xvb[2];
  xva[0] = *(const f32x4*)(xpg + poff0);
  xva[1] = *(const f32x4*)(xpg + poff1);
  xvb[0] = *(const f32x4*)(xpg + 32768 + poff0);
  xvb[1] = *(const f32x4*)(xpg + 32768 + poff1);

  auto step = [&](int t, f32x4 (&xv)[2], int ro, int wo) {
    bf16x8 b[8];
#pragma unroll
    for (int kt = 0; kt < 8; ++kt) b[kt] = *(const bf16x8*)(hb + ro + raddr[kt]);
    f32x4 c0 = xv[0], c1 = xv[1];
#pragma unroll
    for (int kt = 0; kt < 8; ++kt) {
      c0 = __builtin_amdgcn_mfma_f32_16x16x32_bf16(ah[0][kt], b[kt], c0, 0, 0, 0);
      c1 = __builtin_amdgcn_mfma_f32_16x16x32_bf16(ah[1][kt], b[kt], c1, 0, 0, 0);
    }
    {  // refill this parity for t+2 (in flight across the lgkm-only barrier)
      const int tn = (t + 2 <= T_ - 1) ? t + 2 : T_ - 1;
      const float* pb = xpg + (size_t)tn * 32768;
      xv[0] = *(const f32x4*)(pb + poff0);
      xv[1] = *(const f32x4*)(pb + poff1);
    }
    float th[8];
#pragma unroll
    for (int q = 0; q < 8; ++q) th[q] = tanh_fast(q < 4 ? c0[q] : c1[q - 4]);
    uint2 w0 = {cvtpk(th[0], th[1]), cvtpk(th[2], th[3])};
    uint2 w1 = {cvtpk(th[4], th[5]), cvtpk(th[6], th[7])};
    *(uint2*)(hb + wo + waddr[0]) = w0;
    *(uint2*)(hb + wo + waddr[1]) = w1;
    if (HSEQ) {  // contiguous 512B/wave store, never drained
      unsigned short* hp = hsg + (size_t)t * 32768;
      *(uint2*)(hp + poff0) = w0;
      *(uint2*)(hp + poff1) = w1;
    } else if (t == T_ - 1) {  // final hidden state, f32 [128][256] (once)
      float* op = out + (size_t)(g * 16 + lo) * 256 + n0 + hi * 4;
      f32x4 o0 = {th[0], th[1], th[2], th[3]};
      f32x4 o1 = {th[4], th[5], th[6], th[7]};
      *(f32x4*)(op) = o0;
      *(f32x4*)(op + 16) = o1;
    }
    BAR();
  };

  for (int t = 0; t < T_; t += 2) {
    step(t, xva, 8192, 0);      // even: read buf1, write buf0
    step(t + 1, xvb, 0, 8192);  // odd:  read buf0, write buf1
  }
}

extern "C" void kernel_launch(void* const* d_in, const int* in_sizes, int n_in,
                              void* d_out, int out_size, void* d_ws, size_t ws_size,
                              hipStream_t stream) {
  const float* x      = (const float*)d_in[0];
  const float* enc_Wx = (const float*)d_in[1];
  const float* enc_Wh = (const float*)d_in[2];
  const float* enc_b  = (const float*)d_in[3];
  const float* dec_Wx = (const float*)d_in[4];
  const float* dec_Wh = (const float*)d_in[5];
  const float* dec_b  = (const float*)d_in[6];

  char* ws = (char*)d_ws;
  float*          xp   = (float*)ws;                                  // 128MB perm xp_enc (reused as xp_dec)
  unsigned short* hseq = (unsigned short*)(ws + ((size_t)128 << 20)); // 64MB perm bf16 h_seq
  unsigned short* wT   = (unsigned short*)(ws + ((size_t)192 << 20)); // 4 x 128KB bf16 W^T

  // wT layout: [0]=enc_Wx^T  [1]=enc_Wh^T  [2]=dec_Wx^T  [3]=dec_Wh^T
  k_cvt_w<<<1024, 256, 0, stream>>>(enc_Wx, enc_Wh, dec_Wx, dec_Wh, wT);
  // xp_enc = x @ enc_Wx + enc_b  (permuted C; weights amortized 16x)
  k_gemm_x<<<512, 256, 0, stream>>>(x, wT, enc_b, xp);
  // encoder scan -> h_seq (permuted bf16)
  k_scan<true><<<8, 512, 0, stream>>>(xp, wT + 65536, hseq, nullptr);
  // xp_dec = h_seq @ dec_Wx + dec_b  (permuted A and C; overwrites xp)
  k_gemm_h<<<512, 256, 0, stream>>>(hseq, wT + 131072, dec_b, xp);
  // decoder scan -> final hidden state (f32) to d_out
  k_scan<false><<<8, 512, 0, stream>>>(xp, wT + 196608, nullptr, (float*)d_out);
}